// Round 2
// baseline (228.859 us; speedup 1.0000x reference)
//
#include <hip/hip_runtime.h>
#include <math.h>

#define MARGIN 23.0f
#define DIM 256
#define NUM_POS 100000
#define NUM_NEG 100000

#define BLOCK 256
#define WAVES_PER_BLOCK (BLOCK / 64)
#define NBLOCKS 2048     // 2048 blocks x 4 waves = 8192 waves = full wave-slot fill
#define BATCH 4          // rows in flight per wave per iteration (MLP)

// Stage 1: grid-stride over all 200000 rows (positives then negatives).
// One wave per row: lane i loads float4 at element 4*i (64 x 16B = 1KiB,
// fully coalesced). BATCH rows are processed per iteration: all BATCH loads
// issue before any butterfly starts, and the 6-step shfl_xor butterflies for
// the BATCH rows are interleaved for VALU ILP.
//
// ws layout (floats): ws[0] = d_pos[0] fallback;
//                     ws[1 .. NBLOCKS]            = per-block pos max (masked)
//                     ws[1+NBLOCKS .. 2*NBLOCKS]  = per-block neg min
__global__ __launch_bounds__(BLOCK) void triplet_stage1(
    const float* __restrict__ anchor,
    const float* __restrict__ pos,
    const float* __restrict__ neg,
    float* __restrict__ ws) {
  __shared__ float s_pos[WAVES_PER_BLOCK];
  __shared__ float s_neg[WAVES_PER_BLOCK];

  const int lane = threadIdx.x & 63;
  const int wid  = threadIdx.x >> 6;

  const float4 av = reinterpret_cast<const float4*>(anchor)[lane];

  float pos_max = -INFINITY;
  float neg_min =  INFINITY;

  const int gwave  = blockIdx.x * WAVES_PER_BLOCK + wid;
  const int nwaves = NBLOCKS * WAVES_PER_BLOCK;   // 8192
  const int total  = NUM_POS + NUM_NEG;

  for (int base = gwave; base < total; base += nwaves * BATCH) {
    float4 pv[BATCH];
    int    rr[BATCH];
    bool   valid[BATCH];

    // Phase 1: issue all loads (independent, 4 KiB in flight per wave).
    #pragma unroll
    for (int j = 0; j < BATCH; ++j) {
      const int r = base + j * nwaves;
      rr[j] = r;
      valid[j] = (r < total);
      if (valid[j]) {
        const float* row = (r < NUM_POS) ? (pos + (size_t)r * DIM)
                                         : (neg + (size_t)(r - NUM_POS) * DIM);
        pv[j] = reinterpret_cast<const float4*>(row)[lane];
      }
    }

    // Phase 2: per-lane squared diffs.
    float s[BATCH];
    #pragma unroll
    for (int j = 0; j < BATCH; ++j) {
      const float d0 = av.x - pv[j].x;
      const float d1 = av.y - pv[j].y;
      const float d2 = av.z - pv[j].z;
      const float d3 = av.w - pv[j].w;
      s[j] = d0 * d0 + d1 * d1 + d2 * d2 + d3 * d3;
    }

    // Phase 3: interleaved butterflies (BATCH independent chains).
    #pragma unroll
    for (int off = 32; off > 0; off >>= 1) {
      #pragma unroll
      for (int j = 0; j < BATCH; ++j) {
        s[j] += __shfl_xor(s[j], off, 64);
      }
    }

    // Phase 4: update running extrema (branches are wave-uniform).
    #pragma unroll
    for (int j = 0; j < BATCH; ++j) {
      if (!valid[j]) continue;
      const float d = sqrtf(s[j]);
      if (rr[j] < NUM_POS) {
        if (rr[j] == 0 && lane == 0) ws[0] = d;  // fallback d_pos[0]
        if (d < MARGIN) pos_max = fmaxf(pos_max, d);
      } else {
        neg_min = fminf(neg_min, d);
      }
    }
  }

  if (lane == 0) {
    s_pos[wid] = pos_max;
    s_neg[wid] = neg_min;
  }
  __syncthreads();

  if (threadIdx.x == 0) {
    float pm = s_pos[0];
    float nm = s_neg[0];
    #pragma unroll
    for (int i = 1; i < WAVES_PER_BLOCK; ++i) {
      pm = fmaxf(pm, s_pos[i]);
      nm = fminf(nm, s_neg[i]);
    }
    ws[1 + blockIdx.x] = pm;
    ws[1 + NBLOCKS + blockIdx.x] = nm;
  }
}

// Stage 2: one block reduces the NBLOCKS partials and writes the scalar loss.
__global__ __launch_bounds__(BLOCK) void triplet_stage2(
    const float* __restrict__ ws,
    float* __restrict__ out) {
  __shared__ float s_pos[WAVES_PER_BLOCK];
  __shared__ float s_neg[WAVES_PER_BLOCK];

  const int lane = threadIdx.x & 63;
  const int wid  = threadIdx.x >> 6;

  float pm = -INFINITY;
  float nm =  INFINITY;
  for (int i = threadIdx.x; i < NBLOCKS; i += BLOCK) {
    pm = fmaxf(pm, ws[1 + i]);
    nm = fminf(nm, ws[1 + NBLOCKS + i]);
  }
  #pragma unroll
  for (int off = 32; off > 0; off >>= 1) {
    pm = fmaxf(pm, __shfl_xor(pm, off, 64));
    nm = fminf(nm, __shfl_xor(nm, off, 64));
  }
  if (lane == 0) {
    s_pos[wid] = pm;
    s_neg[wid] = nm;
  }
  __syncthreads();
  if (threadIdx.x == 0) {
    float fpm = s_pos[0];
    float fnm = s_neg[0];
    #pragma unroll
    for (int i = 1; i < WAVES_PER_BLOCK; ++i) {
      fpm = fmaxf(fpm, s_pos[i]);
      fnm = fminf(fnm, s_neg[i]);
    }
    if (fpm == -INFINITY) fpm = ws[0];  // no positive under margin -> index 0
    out[0] = fmaxf(fpm - fnm + MARGIN, 0.0f);
  }
}

extern "C" void kernel_launch(void* const* d_in, const int* in_sizes, int n_in,
                              void* d_out, int out_size, void* d_ws, size_t ws_size,
                              hipStream_t stream) {
  const float* anchor = (const float*)d_in[0];
  const float* pos    = (const float*)d_in[1];
  const float* neg    = (const float*)d_in[2];
  float* out = (float*)d_out;
  float* ws  = (float*)d_ws;

  triplet_stage1<<<NBLOCKS, BLOCK, 0, stream>>>(anchor, pos, neg, ws);
  triplet_stage2<<<1, BLOCK, 0, stream>>>(ws, out);
}

// Round 3
// 221.358 us; speedup vs baseline: 1.0339x; 1.0339x over previous
//
#include <hip/hip_runtime.h>
#include <math.h>

#define MARGIN  23.0f
#define MARGIN2 529.0f   // 23^2, exact in f32
#define DIM 256
#define NUM_POS 100000
#define NUM_NEG 100000

#define BLOCK 256
#define WAVES_PER_BLOCK (BLOCK / 64)
#define NBLOCKS 2048

// Stage 1: 16 lanes per row, 4 rows per wave per group.
//   lane = 16*q + t  (q = quarter -> which of the 4 rows, t = segment lane)
//   Each lane loads 4 float4s from its row at 256B stride and accumulates 16
//   squared-diff terms locally. A 4-step shfl_xor butterfly (offsets 1,2,4,8,
//   all within the 16-lane group) then completes FOUR row sums at once:
//   1 DS op per row instead of 6 (the R1/R2 bottleneck), and no sqrt in-loop
//   (squared space: d<23 <=> s<529; max/min are sqrt-monotone).
//
// ws layout (floats, all SQUARED distances):
//   ws[0]                       = d_pos[0]^2 fallback
//   ws[1 .. NBLOCKS]            = per-block pos max (masked)
//   ws[1+NBLOCKS .. 2*NBLOCKS]  = per-block neg min
__global__ __launch_bounds__(BLOCK) void triplet_stage1(
    const float* __restrict__ anchor,
    const float* __restrict__ pos,
    const float* __restrict__ neg,
    float* __restrict__ ws) {
  __shared__ float s_pos[WAVES_PER_BLOCK];
  __shared__ float s_neg[WAVES_PER_BLOCK];

  const int lane = threadIdx.x & 63;
  const int wid  = threadIdx.x >> 6;
  const int t    = lane & 15;   // segment within row
  const int q    = lane >> 4;   // which row of the group's 4

  // Anchor fragments: elements [i*64 + t*4 .. +3], same for all quarters.
  const float4* af = reinterpret_cast<const float4*>(anchor);
  const float4 a0 = af[t];
  const float4 a1 = af[t + 16];
  const float4 a2 = af[t + 32];
  const float4 a3 = af[t + 48];

  float pmax = -INFINITY;  // squared space
  float nmin =  INFINITY;

  const int gwave = blockIdx.x * WAVES_PER_BLOCK + wid;
  const int nw    = NBLOCKS * WAVES_PER_BLOCK;   // 8192 waves

  // Positives: 25000 groups of 4 rows.
  for (int g = gwave; g < NUM_POS / 4; g += nw) {
    const float4* rp =
        reinterpret_cast<const float4*>(pos) + (size_t)(g * 4 + q) * (DIM / 4);
    const float4 p0 = rp[t];
    const float4 p1 = rp[t + 16];
    const float4 p2 = rp[t + 32];
    const float4 p3 = rp[t + 48];

    float s;
    {
      const float d00 = a0.x - p0.x, d01 = a0.y - p0.y,
                  d02 = a0.z - p0.z, d03 = a0.w - p0.w;
      const float d10 = a1.x - p1.x, d11 = a1.y - p1.y,
                  d12 = a1.z - p1.z, d13 = a1.w - p1.w;
      const float d20 = a2.x - p2.x, d21 = a2.y - p2.y,
                  d22 = a2.z - p2.z, d23 = a2.w - p2.w;
      const float d30 = a3.x - p3.x, d31 = a3.y - p3.y,
                  d32 = a3.z - p3.z, d33 = a3.w - p3.w;
      const float s0 = d00 * d00 + d01 * d01 + d02 * d02 + d03 * d03;
      const float s1 = d10 * d10 + d11 * d11 + d12 * d12 + d13 * d13;
      const float s2 = d20 * d20 + d21 * d21 + d22 * d22 + d23 * d23;
      const float s3 = d30 * d30 + d31 * d31 + d32 * d32 + d33 * d33;
      s = (s0 + s1) + (s2 + s3);
    }
    // Complete 4 row-sums with 4 shuffles (within-16 butterfly).
    s += __shfl_xor(s, 1, 64);
    s += __shfl_xor(s, 2, 64);
    s += __shfl_xor(s, 4, 64);
    s += __shfl_xor(s, 8, 64);

    if (g == 0 && lane == 0) ws[0] = s;  // row 0 fallback (squared)
    if (s < MARGIN2) pmax = fmaxf(pmax, s);
  }

  // Negatives: 25000 groups of 4 rows.
  for (int g = gwave; g < NUM_NEG / 4; g += nw) {
    const float4* rp =
        reinterpret_cast<const float4*>(neg) + (size_t)(g * 4 + q) * (DIM / 4);
    const float4 p0 = rp[t];
    const float4 p1 = rp[t + 16];
    const float4 p2 = rp[t + 32];
    const float4 p3 = rp[t + 48];

    float s;
    {
      const float d00 = a0.x - p0.x, d01 = a0.y - p0.y,
                  d02 = a0.z - p0.z, d03 = a0.w - p0.w;
      const float d10 = a1.x - p1.x, d11 = a1.y - p1.y,
                  d12 = a1.z - p1.z, d13 = a1.w - p1.w;
      const float d20 = a2.x - p2.x, d21 = a2.y - p2.y,
                  d22 = a2.z - p2.z, d23 = a2.w - p2.w;
      const float d30 = a3.x - p3.x, d31 = a3.y - p3.y,
                  d32 = a3.z - p3.z, d33 = a3.w - p3.w;
      const float s0 = d00 * d00 + d01 * d01 + d02 * d02 + d03 * d03;
      const float s1 = d10 * d10 + d11 * d11 + d12 * d12 + d13 * d13;
      const float s2 = d20 * d20 + d21 * d21 + d22 * d22 + d23 * d23;
      const float s3 = d30 * d30 + d31 * d31 + d32 * d32 + d33 * d33;
      s = (s0 + s1) + (s2 + s3);
    }
    s += __shfl_xor(s, 1, 64);
    s += __shfl_xor(s, 2, 64);
    s += __shfl_xor(s, 4, 64);
    s += __shfl_xor(s, 8, 64);

    nmin = fminf(nmin, s);
  }

  // Cross-quarter combine: lanes within a quarter are identical, so only
  // offsets 16 and 32 are needed.
  pmax = fmaxf(pmax, __shfl_xor(pmax, 16, 64));
  pmax = fmaxf(pmax, __shfl_xor(pmax, 32, 64));
  nmin = fminf(nmin, __shfl_xor(nmin, 16, 64));
  nmin = fminf(nmin, __shfl_xor(nmin, 32, 64));

  if (lane == 0) {
    s_pos[wid] = pmax;
    s_neg[wid] = nmin;
  }
  __syncthreads();

  if (threadIdx.x == 0) {
    float pm = s_pos[0];
    float nm = s_neg[0];
    #pragma unroll
    for (int i = 1; i < WAVES_PER_BLOCK; ++i) {
      pm = fmaxf(pm, s_pos[i]);
      nm = fminf(nm, s_neg[i]);
    }
    ws[1 + blockIdx.x] = pm;
    ws[1 + NBLOCKS + blockIdx.x] = nm;
  }
}

// Stage 2: reduce NBLOCKS partials (squared space), sqrt once, write loss.
__global__ __launch_bounds__(BLOCK) void triplet_stage2(
    const float* __restrict__ ws,
    float* __restrict__ out) {
  __shared__ float s_pos[WAVES_PER_BLOCK];
  __shared__ float s_neg[WAVES_PER_BLOCK];

  const int lane = threadIdx.x & 63;
  const int wid  = threadIdx.x >> 6;

  float pm = -INFINITY;
  float nm =  INFINITY;
  for (int i = threadIdx.x; i < NBLOCKS; i += BLOCK) {
    pm = fmaxf(pm, ws[1 + i]);
    nm = fminf(nm, ws[1 + NBLOCKS + i]);
  }
  #pragma unroll
  for (int off = 32; off > 0; off >>= 1) {
    pm = fmaxf(pm, __shfl_xor(pm, off, 64));
    nm = fminf(nm, __shfl_xor(nm, off, 64));
  }
  if (lane == 0) {
    s_pos[wid] = pm;
    s_neg[wid] = nm;
  }
  __syncthreads();
  if (threadIdx.x == 0) {
    float fpm = s_pos[0];
    float fnm = s_neg[0];
    #pragma unroll
    for (int i = 1; i < WAVES_PER_BLOCK; ++i) {
      fpm = fmaxf(fpm, s_pos[i]);
      fnm = fminf(fnm, s_neg[i]);
    }
    if (fpm == -INFINITY) fpm = ws[0];  // no positive under margin -> index 0
    out[0] = fmaxf(sqrtf(fpm) - sqrtf(fnm) + MARGIN, 0.0f);
  }
}

extern "C" void kernel_launch(void* const* d_in, const int* in_sizes, int n_in,
                              void* d_out, int out_size, void* d_ws, size_t ws_size,
                              hipStream_t stream) {
  const float* anchor = (const float*)d_in[0];
  const float* pos    = (const float*)d_in[1];
  const float* neg    = (const float*)d_in[2];
  float* out = (float*)d_out;
  float* ws  = (float*)d_ws;

  triplet_stage1<<<NBLOCKS, BLOCK, 0, stream>>>(anchor, pos, neg, ws);
  triplet_stage2<<<1, BLOCK, 0, stream>>>(ws, out);
}

// Round 4
// 203.790 us; speedup vs baseline: 1.1230x; 1.0862x over previous
//
#include <hip/hip_runtime.h>
#include <math.h>

#define MARGIN  23.0f
#define MARGIN2 529.0f   // 23^2, exact in f32
#define DIM 256
#define NUM_POS 100000
#define NUM_NEG 100000

#define BLOCK 256
#define WAVES_PER_BLOCK (BLOCK / 64)
#define NBLOCKS 2048

typedef float v4f __attribute__((ext_vector_type(4)));

// Stage 1: 16 lanes per row, 4 rows per wave per group (as R3), plus:
//  - NON-TEMPORAL loads on the pool rows (data is touched exactly once per
//    launch; R1-R3 showed the L3 half-hit/half-miss fill path caps at
//    ~1.4 TB/s effective — bypass it and stream from HBM).
//  - one-deep software pipeline: group g+1's 4 loads are issued before
//    group g's shuffle reduction, keeping VMEM busy through the DS chain.
//
// ws layout (floats, all SQUARED distances):
//   ws[0]                       = d_pos[0]^2 fallback
//   ws[1 .. NBLOCKS]            = per-block pos max (masked)
//   ws[1+NBLOCKS .. 2*NBLOCKS]  = per-block neg min
__global__ __launch_bounds__(BLOCK) void triplet_stage1(
    const float* __restrict__ anchor,
    const float* __restrict__ pos,
    const float* __restrict__ neg,
    float* __restrict__ ws) {
  __shared__ float s_pos[WAVES_PER_BLOCK];
  __shared__ float s_neg[WAVES_PER_BLOCK];

  const int lane = threadIdx.x & 63;
  const int wid  = threadIdx.x >> 6;
  const int t    = lane & 15;   // segment within row
  const int q    = lane >> 4;   // which row of the group's 4

  // Anchor fragments (reused; normal cached loads).
  const v4f* af = reinterpret_cast<const v4f*>(anchor);
  const v4f a0 = af[t];
  const v4f a1 = af[t + 16];
  const v4f a2 = af[t + 32];
  const v4f a3 = af[t + 48];

  float pmax = -INFINITY;  // squared space
  float nmin =  INFINITY;

  const int gwave = blockIdx.x * WAVES_PER_BLOCK + wid;
  const int nw    = NBLOCKS * WAVES_PER_BLOCK;   // 8192 waves
  const int GP    = NUM_POS / 4;                 // 25000 groups
  const int GN    = NUM_NEG / 4;

  // ---------------- positives ----------------
  {
    int g = gwave;
    v4f p0, p1, p2, p3;
    if (g < GP) {
      const v4f* rp = reinterpret_cast<const v4f*>(pos) +
                      (size_t)(g * 4 + q) * (DIM / 4);
      p0 = __builtin_nontemporal_load(rp + t);
      p1 = __builtin_nontemporal_load(rp + t + 16);
      p2 = __builtin_nontemporal_load(rp + t + 32);
      p3 = __builtin_nontemporal_load(rp + t + 48);
    }
    while (g < GP) {
      const int gn = g + nw;
      v4f q0, q1, q2, q3;
      if (gn < GP) {  // prefetch next group before reducing current
        const v4f* rp = reinterpret_cast<const v4f*>(pos) +
                        (size_t)(gn * 4 + q) * (DIM / 4);
        q0 = __builtin_nontemporal_load(rp + t);
        q1 = __builtin_nontemporal_load(rp + t + 16);
        q2 = __builtin_nontemporal_load(rp + t + 32);
        q3 = __builtin_nontemporal_load(rp + t + 48);
      }
      v4f d0 = a0 - p0, d1 = a1 - p1, d2 = a2 - p2, d3 = a3 - p3;
      float s = (d0.x * d0.x + d0.y * d0.y + d0.z * d0.z + d0.w * d0.w) +
                (d1.x * d1.x + d1.y * d1.y + d1.z * d1.z + d1.w * d1.w) +
                (d2.x * d2.x + d2.y * d2.y + d2.z * d2.z + d2.w * d2.w) +
                (d3.x * d3.x + d3.y * d3.y + d3.z * d3.z + d3.w * d3.w);
      s += __shfl_xor(s, 1, 64);
      s += __shfl_xor(s, 2, 64);
      s += __shfl_xor(s, 4, 64);
      s += __shfl_xor(s, 8, 64);

      if (g == 0 && lane == 0) ws[0] = s;  // row 0 fallback (squared)
      if (s < MARGIN2) pmax = fmaxf(pmax, s);

      p0 = q0; p1 = q1; p2 = q2; p3 = q3;
      g = gn;
    }
  }

  // ---------------- negatives ----------------
  {
    int g = gwave;
    v4f p0, p1, p2, p3;
    if (g < GN) {
      const v4f* rp = reinterpret_cast<const v4f*>(neg) +
                      (size_t)(g * 4 + q) * (DIM / 4);
      p0 = __builtin_nontemporal_load(rp + t);
      p1 = __builtin_nontemporal_load(rp + t + 16);
      p2 = __builtin_nontemporal_load(rp + t + 32);
      p3 = __builtin_nontemporal_load(rp + t + 48);
    }
    while (g < GN) {
      const int gn = g + nw;
      v4f q0, q1, q2, q3;
      if (gn < GN) {
        const v4f* rp = reinterpret_cast<const v4f*>(neg) +
                        (size_t)(gn * 4 + q) * (DIM / 4);
        q0 = __builtin_nontemporal_load(rp + t);
        q1 = __builtin_nontemporal_load(rp + t + 16);
        q2 = __builtin_nontemporal_load(rp + t + 32);
        q3 = __builtin_nontemporal_load(rp + t + 48);
      }
      v4f d0 = a0 - p0, d1 = a1 - p1, d2 = a2 - p2, d3 = a3 - p3;
      float s = (d0.x * d0.x + d0.y * d0.y + d0.z * d0.z + d0.w * d0.w) +
                (d1.x * d1.x + d1.y * d1.y + d1.z * d1.z + d1.w * d1.w) +
                (d2.x * d2.x + d2.y * d2.y + d2.z * d2.z + d2.w * d2.w) +
                (d3.x * d3.x + d3.y * d3.y + d3.z * d3.z + d3.w * d3.w);
      s += __shfl_xor(s, 1, 64);
      s += __shfl_xor(s, 2, 64);
      s += __shfl_xor(s, 4, 64);
      s += __shfl_xor(s, 8, 64);

      nmin = fminf(nmin, s);

      p0 = q0; p1 = q1; p2 = q2; p3 = q3;
      g = gn;
    }
  }

  // Cross-quarter combine (lanes within a quarter are identical).
  pmax = fmaxf(pmax, __shfl_xor(pmax, 16, 64));
  pmax = fmaxf(pmax, __shfl_xor(pmax, 32, 64));
  nmin = fminf(nmin, __shfl_xor(nmin, 16, 64));
  nmin = fminf(nmin, __shfl_xor(nmin, 32, 64));

  if (lane == 0) {
    s_pos[wid] = pmax;
    s_neg[wid] = nmin;
  }
  __syncthreads();

  if (threadIdx.x == 0) {
    float pm = s_pos[0];
    float nm = s_neg[0];
    #pragma unroll
    for (int i = 1; i < WAVES_PER_BLOCK; ++i) {
      pm = fmaxf(pm, s_pos[i]);
      nm = fminf(nm, s_neg[i]);
    }
    ws[1 + blockIdx.x] = pm;
    ws[1 + NBLOCKS + blockIdx.x] = nm;
  }
}

// Stage 2: reduce NBLOCKS partials (squared space), sqrt once, write loss.
__global__ __launch_bounds__(BLOCK) void triplet_stage2(
    const float* __restrict__ ws,
    float* __restrict__ out) {
  __shared__ float s_pos[WAVES_PER_BLOCK];
  __shared__ float s_neg[WAVES_PER_BLOCK];

  const int lane = threadIdx.x & 63;
  const int wid  = threadIdx.x >> 6;

  float pm = -INFINITY;
  float nm =  INFINITY;
  for (int i = threadIdx.x; i < NBLOCKS; i += BLOCK) {
    pm = fmaxf(pm, ws[1 + i]);
    nm = fminf(nm, ws[1 + NBLOCKS + i]);
  }
  #pragma unroll
  for (int off = 32; off > 0; off >>= 1) {
    pm = fmaxf(pm, __shfl_xor(pm, off, 64));
    nm = fminf(nm, __shfl_xor(nm, off, 64));
  }
  if (lane == 0) {
    s_pos[wid] = pm;
    s_neg[wid] = nm;
  }
  __syncthreads();
  if (threadIdx.x == 0) {
    float fpm = s_pos[0];
    float fnm = s_neg[0];
    #pragma unroll
    for (int i = 1; i < WAVES_PER_BLOCK; ++i) {
      fpm = fmaxf(fpm, s_pos[i]);
      fnm = fminf(fnm, s_neg[i]);
    }
    if (fpm == -INFINITY) fpm = ws[0];  // no positive under margin -> index 0
    out[0] = fmaxf(sqrtf(fpm) - sqrtf(fnm) + MARGIN, 0.0f);
  }
}

extern "C" void kernel_launch(void* const* d_in, const int* in_sizes, int n_in,
                              void* d_out, int out_size, void* d_ws, size_t ws_size,
                              hipStream_t stream) {
  const float* anchor = (const float*)d_in[0];
  const float* pos    = (const float*)d_in[1];
  const float* neg    = (const float*)d_in[2];
  float* out = (float*)d_out;
  float* ws  = (float*)d_ws;

  triplet_stage1<<<NBLOCKS, BLOCK, 0, stream>>>(anchor, pos, neg, ws);
  triplet_stage2<<<1, BLOCK, 0, stream>>>(ws, out);
}

// Round 5
// 202.033 us; speedup vs baseline: 1.1328x; 1.0087x over previous
//
#include <hip/hip_runtime.h>
#include <math.h>

#define MARGIN  23.0f
#define MARGIN2 529.0f   // 23^2, exact in f32
#define DIM 256
#define NUM_POS 100000
#define NUM_NEG 100000

#define BLOCK 256
#define WAVES_PER_BLOCK (BLOCK / 64)
#define NBLOCKS 1792                     // 7 blocks/CU x 256 CUs, all co-resident
#define NW (NBLOCKS * WAVES_PER_BLOCK)   // 7168 waves
#define GP (NUM_POS / 4)                 // 25000 pos groups (4 rows each)
#define GTOT ((NUM_POS + NUM_NEG) / 4)   // 50000 groups total

typedef float v4f __attribute__((ext_vector_type(4)));

// Stage 1: 16 lanes per row, 4 rows (one group) per wave iteration.
// R5: single merged group space [0,50000) (pos then neg), STATIC CONTIGUOUS
// per-wave partition: 50000/7168 = 6.98 -> 6992 waves do 7 groups, 176 do 6
// (R4's two 25000-group grid-stride loops quantized to 3-vs-4 iterations
// twice -> ~30% tail; this is ~0.3%). Non-temporal loads (one-touch stream,
// bypass the L3 half-hit fill path) + depth-1 prefetch retained from R4.
//
// ws layout (floats, all SQUARED distances):
//   ws[0]                       = d_pos[0]^2 fallback
//   ws[1 .. NBLOCKS]            = per-block pos max (masked)
//   ws[1+NBLOCKS .. 2*NBLOCKS]  = per-block neg min
__global__ __launch_bounds__(BLOCK, 7) void triplet_stage1(
    const float* __restrict__ anchor,
    const float* __restrict__ pos,
    const float* __restrict__ neg,
    float* __restrict__ ws) {
  __shared__ float s_pos[WAVES_PER_BLOCK];
  __shared__ float s_neg[WAVES_PER_BLOCK];

  const int lane = threadIdx.x & 63;
  const int wid  = threadIdx.x >> 6;
  const int t    = lane & 15;   // segment within row
  const int q    = lane >> 4;   // which row of the group's 4

  // Anchor fragments (reused; normal cached loads).
  const v4f* af = reinterpret_cast<const v4f*>(anchor);
  const v4f a0 = af[t];
  const v4f a1 = af[t + 16];
  const v4f a2 = af[t + 32];
  const v4f a3 = af[t + 48];

  float pmax = -INFINITY;  // squared space
  float nmin =  INFINITY;

  // Static contiguous partition of GTOT groups over NW waves.
  const int w   = blockIdx.x * WAVES_PER_BLOCK + wid;
  const int qg  = GTOT / NW;                  // 6
  const int rg  = GTOT - qg * NW;             // 6992
  const int start = w * qg + (w < rg ? w : rg);
  const int count = qg + (w < rg ? 1 : 0);

  // Depth-1 software pipeline over the wave's contiguous range.
  int g = start;
  v4f p0, p1, p2, p3;
  {
    const float* base = (g < GP) ? (pos + (size_t)g * 4 * DIM)
                                 : (neg + (size_t)(g - GP) * 4 * DIM);
    const v4f* rp = reinterpret_cast<const v4f*>(base) + (size_t)q * (DIM / 4);
    p0 = __builtin_nontemporal_load(rp + t);
    p1 = __builtin_nontemporal_load(rp + t + 16);
    p2 = __builtin_nontemporal_load(rp + t + 32);
    p3 = __builtin_nontemporal_load(rp + t + 48);
  }

  for (int i = 0; i < count; ++i) {
    v4f n0, n1, n2, n3;
    if (i + 1 < count) {  // prefetch next group before reducing current
      const int gn = g + 1;
      const float* base = (gn < GP) ? (pos + (size_t)gn * 4 * DIM)
                                    : (neg + (size_t)(gn - GP) * 4 * DIM);
      const v4f* rp = reinterpret_cast<const v4f*>(base) + (size_t)q * (DIM / 4);
      n0 = __builtin_nontemporal_load(rp + t);
      n1 = __builtin_nontemporal_load(rp + t + 16);
      n2 = __builtin_nontemporal_load(rp + t + 32);
      n3 = __builtin_nontemporal_load(rp + t + 48);
    }

    v4f d0 = a0 - p0, d1 = a1 - p1, d2 = a2 - p2, d3 = a3 - p3;
    float s = (d0.x * d0.x + d0.y * d0.y + d0.z * d0.z + d0.w * d0.w) +
              (d1.x * d1.x + d1.y * d1.y + d1.z * d1.z + d1.w * d1.w) +
              (d2.x * d2.x + d2.y * d2.y + d2.z * d2.z + d2.w * d2.w) +
              (d3.x * d3.x + d3.y * d3.y + d3.z * d3.z + d3.w * d3.w);
    // Complete 4 row-sums with 4 shuffles (within-16 butterfly).
    s += __shfl_xor(s, 1, 64);
    s += __shfl_xor(s, 2, 64);
    s += __shfl_xor(s, 4, 64);
    s += __shfl_xor(s, 8, 64);

    if (g < GP) {
      if (g == 0 && lane == 0) ws[0] = s;  // row 0 fallback (squared)
      if (s < MARGIN2) pmax = fmaxf(pmax, s);
    } else {
      nmin = fminf(nmin, s);
    }

    p0 = n0; p1 = n1; p2 = n2; p3 = n3;
    ++g;
  }

  // Cross-quarter combine (lanes within a quarter hold identical values).
  pmax = fmaxf(pmax, __shfl_xor(pmax, 16, 64));
  pmax = fmaxf(pmax, __shfl_xor(pmax, 32, 64));
  nmin = fminf(nmin, __shfl_xor(nmin, 16, 64));
  nmin = fminf(nmin, __shfl_xor(nmin, 32, 64));

  if (lane == 0) {
    s_pos[wid] = pmax;
    s_neg[wid] = nmin;
  }
  __syncthreads();

  if (threadIdx.x == 0) {
    float pm = s_pos[0];
    float nm = s_neg[0];
    #pragma unroll
    for (int i = 1; i < WAVES_PER_BLOCK; ++i) {
      pm = fmaxf(pm, s_pos[i]);
      nm = fminf(nm, s_neg[i]);
    }
    ws[1 + blockIdx.x] = pm;
    ws[1 + NBLOCKS + blockIdx.x] = nm;
  }
}

// Stage 2: reduce NBLOCKS partials (squared space), sqrt once, write loss.
__global__ __launch_bounds__(BLOCK) void triplet_stage2(
    const float* __restrict__ ws,
    float* __restrict__ out) {
  __shared__ float s_pos[WAVES_PER_BLOCK];
  __shared__ float s_neg[WAVES_PER_BLOCK];

  const int lane = threadIdx.x & 63;
  const int wid  = threadIdx.x >> 6;

  float pm = -INFINITY;
  float nm =  INFINITY;
  for (int i = threadIdx.x; i < NBLOCKS; i += BLOCK) {
    pm = fmaxf(pm, ws[1 + i]);
    nm = fminf(nm, ws[1 + NBLOCKS + i]);
  }
  #pragma unroll
  for (int off = 32; off > 0; off >>= 1) {
    pm = fmaxf(pm, __shfl_xor(pm, off, 64));
    nm = fminf(nm, __shfl_xor(nm, off, 64));
  }
  if (lane == 0) {
    s_pos[wid] = pm;
    s_neg[wid] = nm;
  }
  __syncthreads();
  if (threadIdx.x == 0) {
    float fpm = s_pos[0];
    float fnm = s_neg[0];
    #pragma unroll
    for (int i = 1; i < WAVES_PER_BLOCK; ++i) {
      fpm = fmaxf(fpm, s_pos[i]);
      fnm = fminf(fnm, s_neg[i]);
    }
    if (fpm == -INFINITY) fpm = ws[0];  // no positive under margin -> index 0
    out[0] = fmaxf(sqrtf(fpm) - sqrtf(fnm) + MARGIN, 0.0f);
  }
}

extern "C" void kernel_launch(void* const* d_in, const int* in_sizes, int n_in,
                              void* d_out, int out_size, void* d_ws, size_t ws_size,
                              hipStream_t stream) {
  const float* anchor = (const float*)d_in[0];
  const float* pos    = (const float*)d_in[1];
  const float* neg    = (const float*)d_in[2];
  float* out = (float*)d_out;
  float* ws  = (float*)d_ws;

  triplet_stage1<<<NBLOCKS, BLOCK, 0, stream>>>(anchor, pos, neg, ws);
  triplet_stage2<<<1, BLOCK, 0, stream>>>(ws, out);
}